// Round 10
// baseline (2330.653 us; speedup 1.0000x reference)
//
#include <hip/hip_runtime.h>
#include <hip/hip_bf16.h>
#include <type_traits>

#define T_ 256
#define B_ 128
#define DIN_ 512
#define H_ 1024
#define DOUT_ 512

typedef __attribute__((ext_vector_type(8))) short bf16x8;
typedef __attribute__((ext_vector_type(4))) short s16x4;
typedef __attribute__((ext_vector_type(4))) float f32x4;
typedef __attribute__((ext_vector_type(2))) unsigned long long u64x2;
typedef unsigned long long u64;

__device__ inline short f2bf(float f) {
    return __builtin_bit_cast(short, __float2bfloat16(f));
}
__device__ inline float4 zload4(const short* p) {
    u64 u = *(const u64*)p;
    auto bf = [](unsigned x) { return __builtin_bit_cast(float, x << 16); };
    return make_float4(bf((unsigned)(u & 0xffff) ), bf((unsigned)((u >> 16) & 0xffff)),
                       bf((unsigned)((u >> 32) & 0xffff)), bf((unsigned)((u >> 48) & 0xffff)));
}
__device__ inline u64 pack4bf(float v0, float v1, float v2, float v3) {
    return (u64)(unsigned short)f2bf(v0)
         | ((u64)(unsigned short)f2bf(v1) << 16)
         | ((u64)(unsigned short)f2bf(v2) << 32)
         | ((u64)(unsigned short)f2bf(v3) << 48);
}

// Chunk-granular dataflow (round 10):
//   - hbuf slots are SELF-VALIDATING: relu(h) >= 0 -> bf16 sign bit carries a
//     period-2 step-parity tag. 8B atomic store = all-or-nothing publish.
//   - consumers spin per 64-col chunk on exactly the 4 slots they need next
//     (NOT all slots -- round-7's storm; NOT flag+bulk-stage -- round-6's
//     barrier chain). Early chunks hit on the first load; only the last
//     producer's chunk costs a wait. No flags, no barriers, no LDS.
//   - publish is a plain relaxed sc1 atomic store: a self-validating slot has
//     nothing to order against (round-5 store-vs-flag hazard is void).
//   - WAR (2 buffers): wave publishes h(t-1) only after consuming ALL of
//     t-2; a producer of t needs every wave's t-1 chunk, so t-2 is dead
//     before overwrite. Monotonic dataflow -> deadlock-free, deterministic.
#define AT_LD64(p)    __hip_atomic_load((p), __ATOMIC_RELAXED, __HIP_MEMORY_SCOPE_AGENT)
#define AT_ST64(p, v) __hip_atomic_store((p), (v), __ATOMIC_RELAXED, __HIP_MEMORY_SCOPE_AGENT)

// ---------------------------------------------------------------------------
// Generic GEMM: out[M][N] = A[M][K] * W[N][K]^T + b1 (+ b2), bf16 MFMA.
// (unchanged -- validated rounds 1/3/4/5/6/7/9)
// ---------------------------------------------------------------------------
template <typename OUT_T>
__global__ __launch_bounds__(256)
void gemm_bias(const float* __restrict__ A, const float* __restrict__ W,
               const float* __restrict__ b1, const float* __restrict__ b2,
               OUT_T* __restrict__ out, int M, int N, int K)
{
    __shared__ short lA[4096];
    __shared__ short lB[4096];
    const int ntiles = N >> 7;
    const int bm = blockIdx.x / ntiles;
    const int bn = blockIdx.x % ntiles;
    const size_t m0 = (size_t)bm << 7;
    const size_t n0 = (size_t)bn << 7;
    const int tid = threadIdx.x;
    const int w = tid >> 6, l = tid & 63;
    const int wm = (w >> 1) << 6, wn = (w & 1) << 6;

    f32x4 acc[4][4] = {};
    float4 ra[4], rb[4];

    auto load_regs = [&](int k0) {
#pragma unroll
        for (int i = 0; i < 4; ++i) {
            int s = i * 256 + tid;
            int row = s >> 3, kq = s & 7;
            ra[i] = *(const float4*)(A + (m0 + row) * K + k0 + kq * 4);
            rb[i] = *(const float4*)(W + (n0 + row) * K + k0 + kq * 4);
        }
    };
    auto store_lds = [&]() {
#pragma unroll
        for (int i = 0; i < 4; ++i) {
            int s = i * 256 + tid;
            int row = s >> 3, kq = s & 7;
            int off = ((row >> 4) * 64 + ((row & 15) | ((kq >> 1) << 4))) * 8 + (kq & 1) * 4;
            s16x4 pa = { f2bf(ra[i].x), f2bf(ra[i].y), f2bf(ra[i].z), f2bf(ra[i].w) };
            s16x4 pb = { f2bf(rb[i].x), f2bf(rb[i].y), f2bf(rb[i].z), f2bf(rb[i].w) };
            *(s16x4*)&lA[off] = pa;
            *(s16x4*)&lB[off] = pb;
        }
    };

    load_regs(0);
    const int KI = K >> 5;
    for (int ki = 0; ki < KI; ++ki) {
        __syncthreads();
        store_lds();
        __syncthreads();
        if (ki + 1 < KI) load_regs((ki + 1) << 5);
        bf16x8 aF[4], bF[4];
#pragma unroll
        for (int i = 0; i < 4; ++i) {
            aF[i] = *(const bf16x8*)&lA[(((wm >> 4) + i) * 64 + l) * 8];
            bF[i] = *(const bf16x8*)&lB[(((wn >> 4) + i) * 64 + l) * 8];
        }
#pragma unroll
        for (int i = 0; i < 4; ++i)
#pragma unroll
            for (int j = 0; j < 4; ++j)
                acc[i][j] = __builtin_amdgcn_mfma_f32_16x16x32_bf16(aF[i], bF[j], acc[i][j], 0, 0, 0);
    }

#pragma unroll
    for (int j = 0; j < 4; ++j) {
        const int col = (int)n0 + wn + j * 16 + (l & 15);
        float bb = b1[col];
        if (b2) bb += b2[col];
#pragma unroll
        for (int i = 0; i < 4; ++i) {
#pragma unroll
            for (int r = 0; r < 4; ++r) {
                int row = (int)m0 + wm + i * 16 + (l >> 4) * 4 + r;
                float v = acc[i][j][r] + bb;
                if constexpr (std::is_same<OUT_T, short>::value)
                    out[(size_t)row * N + col] = f2bf(v);
                else
                    out[(size_t)row * N + col] = v;
            }
        }
    }
}

// ---------------------------------------------------------------------------
// Recurrence v10: chunk-granular dataflow, barrier-free.
//   128 WGs = 8 bg (16 batch rows) x 16 cg (64 cols), 4 waves x 16 cols.
//   wh[32] (A-frag) register-resident. Per step each wave walks the 16
//   chunks of h(t-1) (B-frag in hbuf, tagged), spin-loading 4x8B per chunk
//   directly LLC->VGPR, 2 MFMAs per chunk. Publish = tagged 8B sc1 store.
// ---------------------------------------------------------------------------
__global__ __launch_bounds__(256, 1)
void rnn_rec10(const short* __restrict__ zi, const float* __restrict__ Wh,
               float* __restrict__ hidden, unsigned short* __restrict__ hbuf)
{
    const int wg = blockIdx.x;           // 0..127
    const int bg = wg >> 4, cg = wg & 15;
    const int tid = threadIdx.x, w = tid >> 6, l = tid & 63;
    const int b = l & 15, hi = l >> 4;
    const int ocw = cg * 64 + w * 16;    // wave's 16 output columns
    const u64 SIGN = 0x8000800080008000ull;

    // ---- Wh -> registers (A-frag: oc = ocw + (l&15), k = kk*32 + hi*8 + j) ----
    bf16x8 wh[32];
#pragma unroll
    for (int kk = 0; kk < 32; ++kk) {
        const float* wp = Wh + (size_t)(ocw + b) * H_ + kk * 32 + hi * 8;
        float4 a = *(const float4*)wp;
        float4 c = *(const float4*)(wp + 4);
        bf16x8 v = { f2bf(a.x), f2bf(a.y), f2bf(a.z), f2bf(a.w),
                     f2bf(c.x), f2bf(c.y), f2bf(c.z), f2bf(c.w) };
        wh[kk] = v;
    }

    const int f0 = ocw + hi * 4;
    float4 z = zload4(zi + ((size_t)bg * 16 + b) * H_ + f0);

    // hbuf slot bits (B-frag: kk2 = c>>5, lane2 = b | (((c>>3)&3)<<4), j0 = c&7)
    const int kk2 = f0 >> 5, j0 = f0 & 7;
    const int lane2 = b | (((f0 >> 3) & 3) << 4);

#pragma unroll 1
    for (int t = 0; t < T_; ++t) {
        const size_t zb = (size_t)t * B_ * H_;
        f32x4 acc0 = {}, acc1 = {};
        if (t > 0) {
            const u64 expm = (((t - 1) >> 1) & 1) ? SIGN : 0ull;
            const u64* hp = (const u64*)hbuf + (size_t)(((t + 1) & 1) * 8 + bg) * 4096;
#pragma unroll 1
            for (int ci = 0; ci < 16; ++ci) {
                const int c = (cg + ci) & 15;      // stagger across consumers
                const int ka = c * 2;
                const u64* pa = hp + (ka * 64 + l) * 2;
                const u64* pb = pa + 128;          // next kk slice (+64 slots)
                u64 a0, a1, b0, b1;
                do {
                    a0 = AT_LD64(pa);     a1 = AT_LD64(pa + 1);
                    b0 = AT_LD64(pb);     b1 = AT_LD64(pb + 1);
                } while (!__all((int)(((a0 & SIGN) == expm) & ((a1 & SIGN) == expm) &
                                      ((b0 & SIGN) == expm) & ((b1 & SIGN) == expm))));
                if (expm) { a0 &= ~SIGN; a1 &= ~SIGN; b0 &= ~SIGN; b1 &= ~SIGN; }
                u64x2 ua; ua.x = a0; ua.y = a1;
                u64x2 ub; ub.x = b0; ub.y = b1;
                acc0 = __builtin_amdgcn_mfma_f32_16x16x32_bf16(
                           wh[ka], __builtin_bit_cast(bf16x8, ua), acc0, 0, 0, 0);
                acc1 = __builtin_amdgcn_mfma_f32_16x16x32_bf16(
                           wh[ka + 1], __builtin_bit_cast(bf16x8, ub), acc1, 0, 0, 0);
            }
        }
        // ---- epilogue: relu(acc + zi) -> hidden (plain) + hbuf (tagged store) ----
        float v0 = fmaxf(acc0[0] + acc1[0] + z.x, 0.f);
        float v1 = fmaxf(acc0[1] + acc1[1] + z.y, 0.f);
        float v2 = fmaxf(acc0[2] + acc1[2] + z.z, 0.f);
        float v3 = fmaxf(acc0[3] + acc1[3] + z.w, 0.f);
        *(float4*)(hidden + zb + (size_t)(bg * 16 + b) * H_ + f0) =
            make_float4(v0, v1, v2, v3);
        unsigned short* hwS = hbuf + (size_t)((t & 1) * 8 + bg) * 16384;
        u64 pay = pack4bf(v0, v1, v2, v3) | (((t >> 1) & 1) ? SIGN : 0ull);
        AT_ST64((u64*)(hwS + (kk2 * 64 + lane2) * 8 + j0), pay);

        if (t + 1 < T_)                  // prefetch zi(t+1)
            z = zload4(zi + ((size_t)(t + 1) * B_ + bg * 16 + b) * H_ + f0);
    }
}

__global__ __launch_bounds__(256)
void copy_k(const float4* __restrict__ s, float4* __restrict__ d)
{
    int i = blockIdx.x * 256 + threadIdx.x;
    d[i] = s[i];
}

extern "C" void kernel_launch(void* const* d_in, const int* in_sizes, int n_in,
                              void* d_out, int out_size, void* d_ws, size_t ws_size,
                              hipStream_t stream)
{
    const float* x  = (const float*)d_in[0];
    const float* Wi = (const float*)d_in[1];
    const float* bi = (const float*)d_in[2];
    const float* Wh = (const float*)d_in[3];
    const float* bh = (const float*)d_in[4];
    const float* Wo = (const float*)d_in[5];
    const float* bo = (const float*)d_in[6];

    float* hidden = (float*)d_out;                       // [T][B][H]
    float* hT     = hidden + (size_t)T_ * B_ * H_;       // [B][H]
    float* y      = hT + (size_t)B_ * H_;                // [T][B][O]

    const size_t HBUF_B = (size_t)2 * B_ * H_ * sizeof(short);   // 512 KB
    const size_t ZI_B   = (size_t)T_ * B_ * H_ * sizeof(short);  // 64 MB (bf16)

    short* zi;
    unsigned short* hbuf;
    if (ws_size >= HBUF_B + ZI_B) {
        hbuf = (unsigned short*)d_ws;
        zi   = (short*)((char*)d_ws + HBUF_B);
    } else {
        // zi (bf16) in y-section; hbuf in hT-section (both overwritten later)
        zi   = (short*)y;
        hbuf = (unsigned short*)hT;
    }

    // 0xAA: sign=1 everywhere -> t=1/2 consumers (expect tag 0) reject pre-run
    // content. Deterministic across graph replays.
    hipMemsetAsync(hbuf, 0xAA, HBUF_B, stream);

    gemm_bias<short><<<dim3(2048), dim3(256), 0, stream>>>(
        x, Wi, bi, bh, zi, T_ * B_, H_, DIN_);
    rnn_rec10<<<dim3(128), dim3(256), 0, stream>>>(zi, Wh, hidden, hbuf);

    // hT = hidden[T-1]
    copy_k<<<dim3(128), dim3(256), 0, stream>>>(
        (const float4*)(hidden + (size_t)(T_ - 1) * B_ * H_), (float4*)hT);

    // y = hidden @ Wo^T + bo
    gemm_bias<float><<<dim3(1024), dim3(256), 0, stream>>>(
        hidden, Wo, bo, nullptr, y, T_ * B_, DOUT_, H_);
}

// Round 11
// 928.223 us; speedup vs baseline: 2.5109x; 2.5109x over previous
//
#include <hip/hip_runtime.h>
#include <hip/hip_bf16.h>
#include <type_traits>

#define T_ 256
#define B_ 128
#define DIN_ 512
#define H_ 1024
#define DOUT_ 512

typedef __attribute__((ext_vector_type(8))) short bf16x8;
typedef __attribute__((ext_vector_type(4))) short s16x4;
typedef __attribute__((ext_vector_type(4))) float f32x4;
typedef unsigned long long u64;

__device__ inline short f2bf(float f) {
    return __builtin_bit_cast(short, __float2bfloat16(f));
}
__device__ inline float4 zload4(const short* p) {
    u64 u = *(const u64*)p;
    auto bf = [](unsigned x) { return __builtin_bit_cast(float, x << 16); };
    return make_float4(bf((unsigned)(u & 0xffff) ), bf((unsigned)((u >> 16) & 0xffff)),
                       bf((unsigned)((u >> 32) & 0xffff)), bf((unsigned)((u >> 48) & 0xffff)));
}
__device__ inline u64 pack4bf(float v0, float v1, float v2, float v3) {
    return (u64)(unsigned short)f2bf(v0)
         | ((u64)(unsigned short)f2bf(v1) << 16)
         | ((u64)(unsigned short)f2bf(v2) << 32)
         | ((u64)(unsigned short)f2bf(v3) << 48);
}

// Round-11 protocol: tag-validated BULK stage, flag-free.
//   relu(h) >= 0 -> bf16 sign bit carries a period-2 step-parity tag; with 2
//   buffers the (buffer,tag) pair identifies steps mod 4. Epoch proof:
//   consumer progress at step t certifies h(t-3) landed in this slot, so the
//   slot holds h(t-3) (tag mismatch -> retry) or h(t-1) (accept); 0xAA memset
//   (sign=1) is only observable at t in {1,2} where expected tag=0 rejects it.
//   RETRY DISCIPLINE (v7's bug): issue ALL pending loads, then check ALL —
//   one waitcnt per sweep = 1 LLC RTT/sweep, not 16 serialized chains.
//   Publish = plain relaxed sc1 store: self-validating slot, nothing to order
//   against (round-5 hazard void). No flags, no vmcnt drains in the loop.
#define AT_LD64(p)    __hip_atomic_load((p), __ATOMIC_RELAXED, __HIP_MEMORY_SCOPE_AGENT)
#define AT_ST64(p, v) __hip_atomic_store((p), (v), __ATOMIC_RELAXED, __HIP_MEMORY_SCOPE_AGENT)

// ---------------------------------------------------------------------------
// Generic GEMM: out[M][N] = A[M][K] * W[N][K]^T + b1 (+ b2), bf16 MFMA.
// (unchanged -- validated rounds 1/3/4/5/6/7/9/10)
// ---------------------------------------------------------------------------
template <typename OUT_T>
__global__ __launch_bounds__(256)
void gemm_bias(const float* __restrict__ A, const float* __restrict__ W,
               const float* __restrict__ b1, const float* __restrict__ b2,
               OUT_T* __restrict__ out, int M, int N, int K)
{
    __shared__ short lA[4096];
    __shared__ short lB[4096];
    const int ntiles = N >> 7;
    const int bm = blockIdx.x / ntiles;
    const int bn = blockIdx.x % ntiles;
    const size_t m0 = (size_t)bm << 7;
    const size_t n0 = (size_t)bn << 7;
    const int tid = threadIdx.x;
    const int w = tid >> 6, l = tid & 63;
    const int wm = (w >> 1) << 6, wn = (w & 1) << 6;

    f32x4 acc[4][4] = {};
    float4 ra[4], rb[4];

    auto load_regs = [&](int k0) {
#pragma unroll
        for (int i = 0; i < 4; ++i) {
            int s = i * 256 + tid;
            int row = s >> 3, kq = s & 7;
            ra[i] = *(const float4*)(A + (m0 + row) * K + k0 + kq * 4);
            rb[i] = *(const float4*)(W + (n0 + row) * K + k0 + kq * 4);
        }
    };
    auto store_lds = [&]() {
#pragma unroll
        for (int i = 0; i < 4; ++i) {
            int s = i * 256 + tid;
            int row = s >> 3, kq = s & 7;
            int off = ((row >> 4) * 64 + ((row & 15) | ((kq >> 1) << 4))) * 8 + (kq & 1) * 4;
            s16x4 pa = { f2bf(ra[i].x), f2bf(ra[i].y), f2bf(ra[i].z), f2bf(ra[i].w) };
            s16x4 pb = { f2bf(rb[i].x), f2bf(rb[i].y), f2bf(rb[i].z), f2bf(rb[i].w) };
            *(s16x4*)&lA[off] = pa;
            *(s16x4*)&lB[off] = pb;
        }
    };

    load_regs(0);
    const int KI = K >> 5;
    for (int ki = 0; ki < KI; ++ki) {
        __syncthreads();
        store_lds();
        __syncthreads();
        if (ki + 1 < KI) load_regs((ki + 1) << 5);
        bf16x8 aF[4], bF[4];
#pragma unroll
        for (int i = 0; i < 4; ++i) {
            aF[i] = *(const bf16x8*)&lA[(((wm >> 4) + i) * 64 + l) * 8];
            bF[i] = *(const bf16x8*)&lB[(((wn >> 4) + i) * 64 + l) * 8];
        }
#pragma unroll
        for (int i = 0; i < 4; ++i)
#pragma unroll
            for (int j = 0; j < 4; ++j)
                acc[i][j] = __builtin_amdgcn_mfma_f32_16x16x32_bf16(aF[i], bF[j], acc[i][j], 0, 0, 0);
    }

#pragma unroll
    for (int j = 0; j < 4; ++j) {
        const int col = (int)n0 + wn + j * 16 + (l & 15);
        float bb = b1[col];
        if (b2) bb += b2[col];
#pragma unroll
        for (int i = 0; i < 4; ++i) {
#pragma unroll
            for (int r = 0; r < 4; ++r) {
                int row = (int)m0 + wm + i * 16 + (l >> 4) * 4 + r;
                float v = acc[i][j][r] + bb;
                if constexpr (std::is_same<OUT_T, short>::value)
                    out[(size_t)row * N + col] = f2bf(v);
                else
                    out[(size_t)row * N + col] = v;
            }
        }
    }
}

// ---------------------------------------------------------------------------
// Recurrence v11 = v6 bulk-stage structure, flag machinery replaced by
// sign-parity tag validation with issue/check-separated retry sweeps.
//   128 WGs = 8 bg (16 batch rows) x 16 cg (64 cols), 4 waves x 16 cols.
//   wh[32] (A-frag) register-resident, fully static indexing (rule #20).
//   K-loop: 4 accumulator chains (dep depth 8). 2 intra-CU barriers/step.
// ---------------------------------------------------------------------------
__global__ __launch_bounds__(256, 1)
void rnn_rec11(const short* __restrict__ zi, const float* __restrict__ Wh,
               float* __restrict__ hidden, unsigned short* __restrict__ hbuf)
{
    const int wg = blockIdx.x;           // 0..127
    const int bg = wg >> 4, cg = wg & 15;
    const int tid = threadIdx.x, w = tid >> 6, l = tid & 63;
    const int b = l & 15, hi = l >> 4;
    const int ocw = cg * 64 + w * 16;    // wave's 16 output columns
    const u64 SIGN = 0x8000800080008000ull;

    __shared__ u64 lds_h[4096];          // 32 KB: bg's h tile, B-frag layout

    // ---- Wh -> registers (A-frag: oc = ocw + (l&15), k = kk*32 + hi*8 + j) ----
    bf16x8 wh[32];
#pragma unroll
    for (int kk = 0; kk < 32; ++kk) {
        const float* wp = Wh + (size_t)(ocw + b) * H_ + kk * 32 + hi * 8;
        float4 a = *(const float4*)wp;
        float4 c = *(const float4*)(wp + 4);
        bf16x8 v = { f2bf(a.x), f2bf(a.y), f2bf(a.z), f2bf(a.w),
                     f2bf(c.x), f2bf(c.y), f2bf(c.z), f2bf(c.w) };
        wh[kk] = v;
    }

    const int f0 = ocw + hi * 4;
    float4 z = zload4(zi + ((size_t)bg * 16 + b) * H_ + f0);

    // hbuf slot bits (B-frag: kk2 = c>>5, lane2 = b | (((c>>3)&3)<<4), j0 = c&7)
    const int kk2 = f0 >> 5, j0 = f0 & 7;
    const int lane2 = b | (((f0 >> 3) & 3) << 4);

#pragma unroll 1
    for (int t = 0; t < T_; ++t) {
        const size_t zb = (size_t)t * B_ * H_;
        f32x4 c0 = {}, c1 = {}, c2 = {}, c3 = {};
        if (t > 0) {
            const u64 expm = (((t - 1) >> 1) & 1) ? SIGN : 0ull;
            const u64* hp = (const u64*)hbuf + (size_t)(((t + 1) & 1) * 8 + bg) * 4096;
            u64 sv[16];
            // ---- bulk issue: all 16 loads in flight, one waitcnt ----
#pragma unroll
            for (int i = 0; i < 16; ++i)
                sv[i] = AT_LD64(hp + i * 256 + tid);
            // ---- retry sweeps: check-all, reissue-pending (1 RTT/sweep) ----
            unsigned pend = 0xFFFFu;
            while (true) {
                unsigned np = 0;
#pragma unroll
                for (int i = 0; i < 16; ++i)
                    if ((pend & (1u << i)) && (sv[i] & SIGN) != expm)
                        np |= (1u << i);
                pend = np;
                if (!__any((int)pend)) break;
#pragma unroll
                for (int i = 0; i < 16; ++i)
                    if (pend & (1u << i))
                        sv[i] = AT_LD64(hp + i * 256 + tid);
            }
            if (expm) {                  // strip tag bits (set only on odd parity)
#pragma unroll
                for (int i = 0; i < 16; ++i) sv[i] &= ~SIGN;
            }
#pragma unroll
            for (int i = 0; i < 16; ++i)
                lds_h[i * 256 + tid] = sv[i];
            __syncthreads();
            // ---- K-loop: pure LDS + MFMA, 4 chains (dep depth 8) ----
#pragma unroll
            for (int kk = 0; kk < 32; kk += 4) {
                bf16x8 h0 = *(const bf16x8*)&lds_h[((kk + 0) * 64 + l) * 2];
                bf16x8 h1 = *(const bf16x8*)&lds_h[((kk + 1) * 64 + l) * 2];
                bf16x8 h2 = *(const bf16x8*)&lds_h[((kk + 2) * 64 + l) * 2];
                bf16x8 h3 = *(const bf16x8*)&lds_h[((kk + 3) * 64 + l) * 2];
                c0 = __builtin_amdgcn_mfma_f32_16x16x32_bf16(wh[kk + 0], h0, c0, 0, 0, 0);
                c1 = __builtin_amdgcn_mfma_f32_16x16x32_bf16(wh[kk + 1], h1, c1, 0, 0, 0);
                c2 = __builtin_amdgcn_mfma_f32_16x16x32_bf16(wh[kk + 2], h2, c2, 0, 0, 0);
                c3 = __builtin_amdgcn_mfma_f32_16x16x32_bf16(wh[kk + 3], h3, c3, 0, 0, 0);
            }
        }
        // ---- epilogue: relu(acc + zi) -> hidden (plain) + hbuf (tagged store) ----
        float v0 = fmaxf((c0[0] + c1[0]) + (c2[0] + c3[0]) + z.x, 0.f);
        float v1 = fmaxf((c0[1] + c1[1]) + (c2[1] + c3[1]) + z.y, 0.f);
        float v2 = fmaxf((c0[2] + c1[2]) + (c2[2] + c3[2]) + z.z, 0.f);
        float v3 = fmaxf((c0[3] + c1[3]) + (c2[3] + c3[3]) + z.w, 0.f);
        *(float4*)(hidden + zb + (size_t)(bg * 16 + b) * H_ + f0) =
            make_float4(v0, v1, v2, v3);
        unsigned short* hwS = hbuf + (size_t)((t & 1) * 8 + bg) * 16384;
        u64 pay = pack4bf(v0, v1, v2, v3) | (((t >> 1) & 1) ? SIGN : 0ull);
        AT_ST64((u64*)(hwS + (kk2 * 64 + lane2) * 8 + j0), pay);

        if (t + 1 < T_)                  // prefetch zi(t+1)
            z = zload4(zi + ((size_t)(t + 1) * B_ + bg * 16 + b) * H_ + f0);

        __syncthreads();                 // LDS WAR + phase alignment for next stage
    }
}

__global__ __launch_bounds__(256)
void copy_k(const float4* __restrict__ s, float4* __restrict__ d)
{
    int i = blockIdx.x * 256 + threadIdx.x;
    d[i] = s[i];
}

extern "C" void kernel_launch(void* const* d_in, const int* in_sizes, int n_in,
                              void* d_out, int out_size, void* d_ws, size_t ws_size,
                              hipStream_t stream)
{
    const float* x  = (const float*)d_in[0];
    const float* Wi = (const float*)d_in[1];
    const float* bi = (const float*)d_in[2];
    const float* Wh = (const float*)d_in[3];
    const float* bh = (const float*)d_in[4];
    const float* Wo = (const float*)d_in[5];
    const float* bo = (const float*)d_in[6];

    float* hidden = (float*)d_out;                       // [T][B][H]
    float* hT     = hidden + (size_t)T_ * B_ * H_;       // [B][H]
    float* y      = hT + (size_t)B_ * H_;                // [T][B][O]

    const size_t HBUF_B = (size_t)2 * B_ * H_ * sizeof(short);   // 512 KB
    const size_t ZI_B   = (size_t)T_ * B_ * H_ * sizeof(short);  // 64 MB (bf16)

    short* zi;
    unsigned short* hbuf;
    if (ws_size >= HBUF_B + ZI_B) {
        hbuf = (unsigned short*)d_ws;
        zi   = (short*)((char*)d_ws + HBUF_B);
    } else {
        // zi (bf16) in y-section; hbuf in hT-section (both overwritten later)
        zi   = (short*)y;
        hbuf = (unsigned short*)hT;
    }

    // 0xAA: sign=1 everywhere -> t=1/2 consumers (expect tag 0) reject pre-run
    // content; later steps protected by dataflow (see protocol comment).
    hipMemsetAsync(hbuf, 0xAA, HBUF_B, stream);

    gemm_bias<short><<<dim3(2048), dim3(256), 0, stream>>>(
        x, Wi, bi, bh, zi, T_ * B_, H_, DIN_);
    rnn_rec11<<<dim3(128), dim3(256), 0, stream>>>(zi, Wh, hidden, hbuf);

    // hT = hidden[T-1]
    copy_k<<<dim3(128), dim3(256), 0, stream>>>(
        (const float4*)(hidden + (size_t)(T_ - 1) * B_ * H_), (float4*)hT);

    // y = hidden @ Wo^T + bo
    gemm_bias<float><<<dim3(1024), dim3(256), 0, stream>>>(
        hidden, Wo, bo, nullptr, y, T_ * B_, DOUT_, H_);
}

// Round 12
// 861.909 us; speedup vs baseline: 2.7041x; 1.0769x over previous
//
#include <hip/hip_runtime.h>
#include <hip/hip_bf16.h>
#include <type_traits>

#define T_ 256
#define B_ 128
#define DIN_ 512
#define H_ 1024
#define DOUT_ 512

typedef __attribute__((ext_vector_type(8))) short bf16x8;
typedef __attribute__((ext_vector_type(4))) short s16x4;
typedef __attribute__((ext_vector_type(4))) float f32x4;
typedef unsigned long long u64;

__device__ unsigned g_flags[2048];   // 128 WGs x 16-uint stride; zeroed per launch

__device__ inline short f2bf(float f) {
    return __builtin_bit_cast(short, __float2bfloat16(f));
}
__device__ inline float4 zload4(const short* p) {
    u64 u = *(const u64*)p;
    auto bf = [](unsigned x) { return __builtin_bit_cast(float, x << 16); };
    return make_float4(bf((unsigned)(u & 0xffff) ), bf((unsigned)((u >> 16) & 0xffff)),
                       bf((unsigned)((u >> 32) & 0xffff)), bf((unsigned)((u >> 48) & 0xffff)));
}
__device__ inline u64 pack4bf(float v0, float v1, float v2, float v3) {
    return (u64)(unsigned short)f2bf(v0)
         | ((u64)(unsigned short)f2bf(v1) << 16)
         | ((u64)(unsigned short)f2bf(v2) << 32)
         | ((u64)(unsigned short)f2bf(v3) << 48);
}

// Round-6-validated protocol (kept verbatim; v7/v9/v10/v11 all regressed):
//   producer data + flag publishes are atomic EXCHANGES (RMW executes AT the
//   LLC; ack == executed), __syncthreads' vmcnt(0) drain orders data before
//   flag; consumer = single poll wave on 16 flags, then bulk stage once.
#define AT_LD64(p)     __hip_atomic_load((p), __ATOMIC_RELAXED, __HIP_MEMORY_SCOPE_AGENT)
#define AT_SWP64(p, v) (void)__hip_atomic_exchange((p), (v), __ATOMIC_RELAXED, __HIP_MEMORY_SCOPE_AGENT)
#define AT_LD32(p)     __hip_atomic_load((p), __ATOMIC_RELAXED, __HIP_MEMORY_SCOPE_AGENT)
#define AT_SWP32(p, v) (void)__hip_atomic_exchange((p), (v), __ATOMIC_RELAXED, __HIP_MEMORY_SCOPE_AGENT)

__global__ void zero_flags() { g_flags[blockIdx.x * 256 + threadIdx.x] = 0; }

// ---------------------------------------------------------------------------
// Generic GEMM v2: out[M][N] = A[M][K] * W[N][K]^T + b1 (+ b2), bf16 MFMA.
// Round-12 change: BK 32 -> 64 (32 MFMAs per barrier-pair instead of 16).
// Same validated per-32k fragment layout, two k-chunks (kk2) per stage.
// 128x128 tile, 4 waves (2x2), each wave 64x64 (4x4 frags of 16x16x32).
// ---------------------------------------------------------------------------
template <typename OUT_T>
__global__ __launch_bounds__(256)
void gemm_bias(const float* __restrict__ A, const float* __restrict__ W,
               const float* __restrict__ b1, const float* __restrict__ b2,
               OUT_T* __restrict__ out, int M, int N, int K)
{
    __shared__ short lA[8192];   // [mt(8)][kk2(2)][lane(64)][j(8)] bf16, 16 KB
    __shared__ short lB[8192];
    const int ntiles = N >> 7;
    const int bm = blockIdx.x / ntiles;
    const int bn = blockIdx.x % ntiles;
    const size_t m0 = (size_t)bm << 7;
    const size_t n0 = (size_t)bn << 7;
    const int tid = threadIdx.x;
    const int w = tid >> 6, l = tid & 63;
    const int wm = (w >> 1) << 6, wn = (w & 1) << 6;

    f32x4 acc[4][4] = {};
    float4 ra[8], rb[8];

    auto load_regs = [&](int k0) {
#pragma unroll
        for (int i = 0; i < 8; ++i) {
            int s = i * 256 + tid;
            int row = s >> 4, kq = s & 15;           // 128 rows x 16 quads (BK=64)
            ra[i] = *(const float4*)(A + (m0 + row) * K + k0 + kq * 4);
            rb[i] = *(const float4*)(W + (n0 + row) * K + k0 + kq * 4);
        }
    };
    auto store_lds = [&]() {
#pragma unroll
        for (int i = 0; i < 8; ++i) {
            int s = i * 256 + tid;
            int row = s >> 4, kq = s & 15;
            // element (row, k=kq*4..+3): mt=row>>4, kk2=kq>>3,
            // lane=(row&15)|(((kq>>1)&3)<<4), j=(kq&1)*4
            int off = (((row >> 4) * 2 + (kq >> 3)) * 64 +
                       ((row & 15) | (((kq >> 1) & 3) << 4))) * 8 + (kq & 1) * 4;
            s16x4 pa = { f2bf(ra[i].x), f2bf(ra[i].y), f2bf(ra[i].z), f2bf(ra[i].w) };
            s16x4 pb = { f2bf(rb[i].x), f2bf(rb[i].y), f2bf(rb[i].z), f2bf(rb[i].w) };
            *(s16x4*)&lA[off] = pa;
            *(s16x4*)&lB[off] = pb;
        }
    };

    load_regs(0);
    const int KI = K >> 6;
    for (int ki = 0; ki < KI; ++ki) {
        __syncthreads();            // previous iter's frag reads done
        store_lds();
        __syncthreads();
        if (ki + 1 < KI) load_regs((ki + 1) << 6);   // issue early: hides under MFMA
#pragma unroll
        for (int kk2 = 0; kk2 < 2; ++kk2) {
            bf16x8 aF[4], bF[4];
#pragma unroll
            for (int i = 0; i < 4; ++i) {
                aF[i] = *(const bf16x8*)&lA[((((wm >> 4) + i) * 2 + kk2) * 64 + l) * 8];
                bF[i] = *(const bf16x8*)&lB[((((wn >> 4) + i) * 2 + kk2) * 64 + l) * 8];
            }
#pragma unroll
            for (int i = 0; i < 4; ++i)
#pragma unroll
                for (int j = 0; j < 4; ++j)
                    acc[i][j] = __builtin_amdgcn_mfma_f32_16x16x32_bf16(aF[i], bF[j], acc[i][j], 0, 0, 0);
        }
    }

#pragma unroll
    for (int j = 0; j < 4; ++j) {
        const int col = (int)n0 + wn + j * 16 + (l & 15);
        float bb = b1[col];
        if (b2) bb += b2[col];
#pragma unroll
        for (int i = 0; i < 4; ++i) {
#pragma unroll
            for (int r = 0; r < 4; ++r) {
                int row = (int)m0 + wm + i * 16 + (l >> 4) * 4 + r;
                float v = acc[i][j][r] + bb;
                if constexpr (std::is_same<OUT_T, short>::value)
                    out[(size_t)row * N + col] = f2bf(v);
                else
                    out[(size_t)row * N + col] = v;
            }
        }
    }
}

// ---------------------------------------------------------------------------
// Recurrence v6 VERBATIM (round-6 validated, incl. post-timing):
//   128 WGs = 8 bg (16 batch rows) x 16 cg (64 cols), 256 thr (4 waves).
//   Wave owns 16 cols: wh[32] (A-frag) register-resident, no spill.
//   Per step: stage bg's h(t-1) (32 KB, B-frag) LLC->LDS (16x8B/thread),
//   K-loop = ds_read_b128 + MFMA (2 chains). hbuf writes + flag = atomic
//   exchange (executes at LLC). Poll: single wave, relaxed loads.
// ---------------------------------------------------------------------------
__global__ __launch_bounds__(256, 1)
void rnn_rec6(const short* __restrict__ zi, const float* __restrict__ Wh,
              float* __restrict__ hidden, unsigned short* __restrict__ hbuf)
{
    const int wg = blockIdx.x;           // 0..127
    const int bg = wg >> 4, cg = wg & 15;
    const int tid = threadIdx.x, w = tid >> 6, l = tid & 63;
    const int b = l & 15, hi = l >> 4;
    const int ocw = cg * 64 + w * 16;    // wave's 16 output columns

    __shared__ u64 lds_h[4096];          // 32 KB: bg's h tile, B-frag layout

    // ---- Wh -> registers (A-frag: oc = ocw + (l&15), k = kk*32 + hi*8 + j) ----
    bf16x8 wh[32];
#pragma unroll
    for (int kk = 0; kk < 32; ++kk) {
        const float* wp = Wh + (size_t)(ocw + b) * H_ + kk * 32 + hi * 8;
        float4 a = *(const float4*)wp;
        float4 c = *(const float4*)(wp + 4);
        bf16x8 v = { f2bf(a.x), f2bf(a.y), f2bf(a.z), f2bf(a.w),
                     f2bf(c.x), f2bf(c.y), f2bf(c.z), f2bf(c.w) };
        wh[kk] = v;
    }

    const int f0 = ocw + hi * 4;
    float4 z = zload4(zi + ((size_t)bg * 16 + b) * H_ + f0);

    // hbuf slot bits (B-frag: kk2 = c>>5, lane2 = b | (((c>>3)&3)<<4), j0 = c&7)
    const int kk2 = f0 >> 5, j0 = f0 & 7;
    const int lane2 = b | (((f0 >> 3) & 3) << 4);

#pragma unroll 1
    for (int t = 0; t < T_; ++t) {
        const size_t zb = (size_t)t * B_ * H_;
        f32x4 acc0 = {}, acc1 = {};
        if (t > 0) {
            // ---- stage h(t-1): 32 KB from LLC -> LDS (bulk, once) ----
            const u64* hp = (const u64*)hbuf + (size_t)(((t + 1) & 1) * 8 + bg) * 4096;
            u64 sv[16];
#pragma unroll
            for (int i = 0; i < 16; ++i)
                sv[i] = AT_LD64(hp + i * 256 + tid);
#pragma unroll
            for (int i = 0; i < 16; ++i)
                lds_h[i * 256 + tid] = sv[i];
            __syncthreads();
            // ---- K-loop: pure LDS + MFMA, 2 chains ----
#pragma unroll
            for (int kk = 0; kk < 32; ++kk) {
                bf16x8 hbf = *(const bf16x8*)&lds_h[(kk * 64 + l) * 2];
                if (kk & 1)
                    acc1 = __builtin_amdgcn_mfma_f32_16x16x32_bf16(wh[kk], hbf, acc1, 0, 0, 0);
                else
                    acc0 = __builtin_amdgcn_mfma_f32_16x16x32_bf16(wh[kk], hbf, acc0, 0, 0, 0);
            }
        }
        // ---- epilogue: relu(acc + zi) -> hidden (plain) + hbuf (LLC RMW) ----
        float v0 = fmaxf(acc0[0] + acc1[0] + z.x, 0.f);
        float v1 = fmaxf(acc0[1] + acc1[1] + z.y, 0.f);
        float v2 = fmaxf(acc0[2] + acc1[2] + z.z, 0.f);
        float v3 = fmaxf(acc0[3] + acc1[3] + z.w, 0.f);
        *(float4*)(hidden + zb + (size_t)(bg * 16 + b) * H_ + f0) =
            make_float4(v0, v1, v2, v3);
        unsigned short* hwS = hbuf + (size_t)((t & 1) * 8 + bg) * 16384;
        AT_SWP64((u64*)(hwS + (kk2 * 64 + lane2) * 8 + j0), pack4bf(v0, v1, v2, v3));

        __syncthreads();                  // vmcnt(0): RMWs executed AT the LLC
        if (tid == 0)
            AT_SWP32(&g_flags[wg * 16], (unsigned)(t + 1));  // publish (RMW)

        if (t + 1 < T_)                   // prefetch zi(t+1) under the wait
            z = zload4(zi + ((size_t)(t + 1) * B_ + bg * 16 + b) * H_ + f0);

        if (w == 0) {                     // wave 0 polls this bg's 16 producer flags
            const unsigned tgt = (unsigned)(t + 1);
            const unsigned* fp = &g_flags[(bg * 16 + (l & 15)) * 16];
            unsigned v;
            do {
                v = AT_LD32(fp);
            } while (!__all((int)(v >= tgt)));
        }
        __syncthreads();
    }
}

__global__ __launch_bounds__(256)
void copy_k(const float4* __restrict__ s, float4* __restrict__ d)
{
    int i = blockIdx.x * 256 + threadIdx.x;
    d[i] = s[i];
}

extern "C" void kernel_launch(void* const* d_in, const int* in_sizes, int n_in,
                              void* d_out, int out_size, void* d_ws, size_t ws_size,
                              hipStream_t stream)
{
    const float* x  = (const float*)d_in[0];
    const float* Wi = (const float*)d_in[1];
    const float* bi = (const float*)d_in[2];
    const float* Wh = (const float*)d_in[3];
    const float* bh = (const float*)d_in[4];
    const float* Wo = (const float*)d_in[5];
    const float* bo = (const float*)d_in[6];

    float* hidden = (float*)d_out;                       // [T][B][H]
    float* hT     = hidden + (size_t)T_ * B_ * H_;       // [B][H]
    float* y      = hT + (size_t)B_ * H_;                // [T][B][O]

    const size_t HBUF_B = (size_t)2 * B_ * H_ * sizeof(short);   // 512 KB
    const size_t ZI_B   = (size_t)T_ * B_ * H_ * sizeof(short);  // 64 MB (bf16)

    zero_flags<<<dim3(8), dim3(256), 0, stream>>>();

    short* zi;
    unsigned short* hbuf;
    if (ws_size >= HBUF_B + ZI_B) {
        hbuf = (unsigned short*)d_ws;
        zi   = (short*)((char*)d_ws + HBUF_B);
    } else {
        // zi (bf16) in y-section; hbuf in hT-section (both overwritten later)
        zi   = (short*)y;
        hbuf = (unsigned short*)hT;
    }

    gemm_bias<short><<<dim3(2048), dim3(256), 0, stream>>>(
        x, Wi, bi, bh, zi, T_ * B_, H_, DIN_);
    rnn_rec6<<<dim3(128), dim3(256), 0, stream>>>(zi, Wh, hidden, hbuf);

    // hT = hidden[T-1]
    copy_k<<<dim3(128), dim3(256), 0, stream>>>(
        (const float4*)(hidden + (size_t)(T_ - 1) * B_ * H_), (float4*)hT);

    // y = hidden @ Wo^T + bo
    gemm_bias<float><<<dim3(1024), dim3(256), 0, stream>>>(
        hidden, Wo, bo, nullptr, y, T_ * B_, DOUT_, H_);
}